// Round 4
// baseline (195.860 us; speedup 1.0000x reference)
//
#include <hip/hip_runtime.h>
#include <hip/hip_bf16.h>
#include <hip/hip_fp16.h>

// GAT layer on MI355X (gfx950).
//   x: (N=50000, K=256) fp32, W: (K=256, F=64) fp32, a: (1, 128) fp32
//   edge_index: (2, E=1600000) int (src row 0, dst row 1)
// out = elu( segsum_src(e * h[dst]) / segsum_src(e) ),
//   e = exp(-leakyrelu(s_src[src]+s_dst[dst], 0.2)), h = x@W
//
// Round 14: round-13 coop mega-kernel failed in harness (no grid.sync here).
// Back to round-12 verified structure (170us). Two isolated changes:
//  K1: 512-thread blocks. bin identical work/atomics (8 waves split the same
//      4096-edge chunk); gemm 1 row-tile/wave (16 rows) -> 3125 gemm waves
//      (2x round-12). 782 blocks x 8 waves ~ 24 waves/CU (was ~12).
//  K2: gather inner loop unrolled 2->4 independent edge streams (4 loads in
//      flight/lane, VGPR 28->~55, still fits 8 waves/SIMD).

#define ALPHA 0.2f
#define KDIM 256
#define FDIM 64
#define BIN_CHUNK 4096
#define BUCKET_CAP 4096    // 64-src bucket: mean ~2046 edges; >40 sigma slack

typedef __bf16 bf16x8 __attribute__((ext_vector_type(8)));
typedef float f32x4 __attribute__((ext_vector_type(4)));
typedef unsigned int u32;
typedef unsigned short u16;

// ---------------------------------------------------------------------------
// Kernel 0: w_t[n][k] = bf16(W[k][n]) (32 KB, L1-resident) + zero bcur.
// ---------------------------------------------------------------------------
__global__ __launch_bounds__(256) void gat_wt_kernel(
    const float* __restrict__ W, __hip_bfloat16* __restrict__ w_t,
    int* __restrict__ bcur)
{
    const int t = blockIdx.x * 256 + threadIdx.x;
    if (t < KDIM * FDIM) {
        const int k = t >> 6;
        const int n = t & 63;
        w_t[n * KDIM + k] = __float2bfloat16(W[t]);
    }
    if (t < 1024) bcur[t] = 0;
}

// ---------------------------------------------------------------------------
// Kernel 1 (fused): blocks [0,NBLK) = bin; blocks [NBLK, NBLK+GB) = gemm.
// 512 threads/block.
// bin: local hist, one reservation atomic per (block,bucket) on bcur,
//      scatter packed (srclo<<16)|dst into arena pair[b*CAP + slot].
//      (identical work + atomic counts to the verified round-10/12 config)
// gemm: h = bf16(x @ W) via mfma_f32_16x16x32_bf16, scores fp32;
//       1 row-tile (16 rows) per wave, 8 waves -> 128 rows/block.
// ---------------------------------------------------------------------------
__global__ __launch_bounds__(512) void gat_gemm_bin_kernel(
    const float* __restrict__ x, const __hip_bfloat16* __restrict__ w_tp,
    const float* __restrict__ a, __hip_bfloat16* __restrict__ h_bf,
    float* __restrict__ s_src, float* __restrict__ s_dst,
    const int* __restrict__ srcA, const int* __restrict__ dstA,
    int* __restrict__ bcur, u32* __restrict__ pair,
    int N, int E, int NBU, int NBLK)
{
    __shared__ int hist[1024];
    __shared__ int lcur[1024];

    const int t = threadIdx.x;

    if ((int)blockIdx.x < NBLK) {
        // ---------------- bin path ----------------
        for (int j = t; j < 1024; j += 512) hist[j] = 0;
        __syncthreads();
        const int base = blockIdx.x * BIN_CHUNK;
        const int cnt = min(BIN_CHUNK, E - base);
        for (int i = t; i < cnt; i += 512)
            atomicAdd(&hist[srcA[base + i] >> 6], 1);
        __syncthreads();
        for (int j = t; j < NBU; j += 512) {
            const int v = hist[j];
            lcur[j] = v ? (j * BUCKET_CAP + atomicAdd(&bcur[j], v)) : 0;
        }
        __syncthreads();
        for (int i = t; i < cnt; i += 512) {
            const int s = srcA[base + i];
            const int d = dstA[base + i];
            const int pos = atomicAdd(&lcur[s >> 6], 1);
            pair[pos] = ((u32)(s & 63) << 16) | (u32)d;   // d < 65536
        }
        return;
    }

    // ---------------- gemm path ----------------
    const int gb = (int)blockIdx.x - NBLK;
    const int lane = t & 63;
    const int wv = t >> 6;               // 0..7
    const int m0 = gb * 128 + wv * 16;   // this wave: rows m0..m0+15
    const int c = lane & 15;
    const int q = lane >> 4;

    const int r0 = m0 + c;
    const float* xp0 = x + (long)(r0 < N ? r0 : N - 1) * KDIM;
    const __bf16* wt = (const __bf16*)w_tp;

    f32x4 acc[4];
#pragma unroll
    for (int ct = 0; ct < 4; ++ct) acc[ct] = (f32x4){0.f, 0.f, 0.f, 0.f};

#pragma unroll 2
    for (int kc = 0; kc < 8; ++kc) {
        const int k0 = kc * 32 + q * 8;
        const float4 xa0 = *(const float4*)(xp0 + k0);
        const float4 xb0 = *(const float4*)(xp0 + k0 + 4);
        bf16x8 af0;
        af0[0] = (__bf16)xa0.x; af0[1] = (__bf16)xa0.y;
        af0[2] = (__bf16)xa0.z; af0[3] = (__bf16)xa0.w;
        af0[4] = (__bf16)xb0.x; af0[5] = (__bf16)xb0.y;
        af0[6] = (__bf16)xb0.z; af0[7] = (__bf16)xb0.w;
#pragma unroll
        for (int ct = 0; ct < 4; ++ct) {
            const bf16x8 bf = *(const bf16x8*)(wt + (ct * 16 + c) * KDIM + k0);
            acc[ct] = __builtin_amdgcn_mfma_f32_16x16x32_bf16(af0, bf, acc[ct], 0, 0, 0);
        }
    }

    float a1c[4], a2c[4];
#pragma unroll
    for (int ct = 0; ct < 4; ++ct) {
        a1c[ct] = a[ct * 16 + c];
        a2c[ct] = a[FDIM + ct * 16 + c];
    }

    float s1r[4], s2r[4];
#pragma unroll
    for (int reg = 0; reg < 4; ++reg) {
        float s1 = 0.f, s2 = 0.f;
#pragma unroll
        for (int ct = 0; ct < 4; ++ct) {
            s1 += acc[ct][reg] * a1c[ct];
            s2 += acc[ct][reg] * a2c[ct];
        }
        s1r[reg] = s1; s2r[reg] = s2;
    }
#pragma unroll
    for (int off = 1; off < 16; off <<= 1) {
#pragma unroll
        for (int reg = 0; reg < 4; ++reg) {
            s1r[reg] += __shfl_xor(s1r[reg], off);
            s2r[reg] += __shfl_xor(s2r[reg], off);
        }
    }
#pragma unroll
    for (int reg = 0; reg < 4; ++reg) {
        const int row = m0 + q * 4 + reg;
        if (row < N) {
#pragma unroll
            for (int ct = 0; ct < 4; ++ct)
                h_bf[(long)row * FDIM + ct * 16 + c] = __float2bfloat16(acc[ct][reg]);
            if (c == 0) { s_src[row] = s1r[reg]; s_dst[row] = s2r[reg]; }
        }
    }
}

// ---------------------------------------------------------------------------
// Kernel 2 (fused bsort+gather): one block (512 thr) per 64-src bucket.
// Phase A: LDS counting sort of the bucket's pairs + weight pack (stays in
// LDS -- no HBM round-trip). Phase B: segmented reduction over bf16 h from
// the LDS edge list; 4 independent edge streams per lane for latency hiding.
// ---------------------------------------------------------------------------
__global__ __launch_bounds__(512) void gat_sortgather_kernel(
    const u32* __restrict__ pair, const int* __restrict__ bcur,
    const float* __restrict__ s_src, const float* __restrict__ s_dst,
    const __hip_bfloat16* __restrict__ h_bf, float* __restrict__ out, int N)
{
    __shared__ u32 chunk[BUCKET_CAP];   // 16 KB raw pairs
    __shared__ u32 slds[BUCKET_CAP];    // 16 KB sorted (dst | f16(wgt)<<16)
    __shared__ int cur[64];
    __shared__ int nst[64];
    __shared__ int nen[64];
    __shared__ float ssl[64];

    const int b = blockIdx.x;
    const int t = threadIdx.x;
    const int s0 = b << 6;
    const int abase = b * BUCKET_CAP;
    const int n = min(bcur[b], BUCKET_CAP);

    if (t < 64) {
        cur[t] = 0;
        ssl[t] = (s0 + t < N) ? s_src[s0 + t] : 0.f;
    }
    __syncthreads();
    for (int i = t; i < n; i += 512) {
        const u32 p = pair[abase + i];
        chunk[i] = p;
        atomicAdd(&cur[p >> 16], 1);
    }
    __syncthreads();
    if (t < 64) {   // lanes 0..63 of wave 0: exclusive scan of 64 counts
        const int v = cur[t];
        int incl = v;
#pragma unroll
        for (int off = 1; off < 64; off <<= 1) {
            const int nv = __shfl_up(incl, off);
            if (t >= off) incl += nv;
        }
        const int excl = incl - v;
        nst[t] = excl;
        nen[t] = excl + v;
        cur[t] = excl;
    }
    __syncthreads();
    for (int i = t; i < n; i += 512) {
        const u32 p = chunk[i];
        const int sl = p >> 16;
        const int d = (int)(p & 0xFFFFu);
        const int slot = atomicAdd(&cur[sl], 1);
        const float sc = ssl[sl] + s_dst[d];
        const float lr = sc > 0.f ? sc : ALPHA * sc;
        const float wgt = __expf(-lr);
        const u32 wh = (u32)__half_as_ushort(__float2half(wgt));
        slds[slot] = (u32)d | (wh << 16);
    }
    __syncthreads();

    // ---------------- phase B: gather from LDS edge list ----------------
    const int wv = t >> 6;       // 0..7
    const int lane = t & 63;
    const int q = lane >> 3;     // edge slot 0..7
    const int c = lane & 7;      // feature octet 0..7
    const __bf16* hb = (const __bf16*)h_bf;

    for (int nl = wv; nl < 64; nl += 8) {
        const int node = s0 + nl;
        if (node >= N) break;
        const int start = nst[nl];
        const int end = nen[nl];

        float acc0[8], acc1[8], acc2[8], acc3[8];
#pragma unroll
        for (int j = 0; j < 8; ++j) {
            acc0[j] = 0.f; acc1[j] = 0.f; acc2[j] = 0.f; acc3[j] = 0.f;
        }
        float wsum0 = 0.f, wsum1 = 0.f, wsum2 = 0.f, wsum3 = 0.f;

        int e = start + q;
        // 4-stream main loop: 4 loads in flight per lane.
        for (; e + 24 < end; e += 32) {
            const u32 p0 = slds[e];
            const u32 p1 = slds[e + 8];
            const u32 p2 = slds[e + 16];
            const u32 p3 = slds[e + 24];
            const int d0 = (int)(p0 & 0xFFFFu);
            const int d1 = (int)(p1 & 0xFFFFu);
            const int d2 = (int)(p2 & 0xFFFFu);
            const int d3 = (int)(p3 & 0xFFFFu);
            const bf16x8 hv0 = *(const bf16x8*)(hb + (long)d0 * FDIM + 8 * c);
            const bf16x8 hv1 = *(const bf16x8*)(hb + (long)d1 * FDIM + 8 * c);
            const bf16x8 hv2 = *(const bf16x8*)(hb + (long)d2 * FDIM + 8 * c);
            const bf16x8 hv3 = *(const bf16x8*)(hb + (long)d3 * FDIM + 8 * c);
            const float w0 = __half2float(__ushort_as_half((u16)(p0 >> 16)));
            const float w1 = __half2float(__ushort_as_half((u16)(p1 >> 16)));
            const float w2 = __half2float(__ushort_as_half((u16)(p2 >> 16)));
            const float w3 = __half2float(__ushort_as_half((u16)(p3 >> 16)));
#pragma unroll
            for (int j = 0; j < 8; ++j) {
                acc0[j] += w0 * (float)hv0[j];
                acc1[j] += w1 * (float)hv1[j];
                acc2[j] += w2 * (float)hv2[j];
                acc3[j] += w3 * (float)hv3[j];
            }
            wsum0 += w0; wsum1 += w1; wsum2 += w2; wsum3 += w3;
        }
        // 2-stream drain.
        for (; e + 8 < end; e += 16) {
            const u32 p0 = slds[e];
            const u32 p1 = slds[e + 8];
            const int d0 = (int)(p0 & 0xFFFFu);
            const int d1 = (int)(p1 & 0xFFFFu);
            const bf16x8 hv0 = *(const bf16x8*)(hb + (long)d0 * FDIM + 8 * c);
            const bf16x8 hv1 = *(const bf16x8*)(hb + (long)d1 * FDIM + 8 * c);
            const float w0 = __half2float(__ushort_as_half((u16)(p0 >> 16)));
            const float w1 = __half2float(__ushort_as_half((u16)(p1 >> 16)));
#pragma unroll
            for (int j = 0; j < 8; ++j) {
                acc0[j] += w0 * (float)hv0[j];
                acc1[j] += w1 * (float)hv1[j];
            }
            wsum0 += w0; wsum1 += w1;
        }
        // 1-edge tail.
        if (e < end) {
            const u32 p0 = slds[e];
            const int d0 = (int)(p0 & 0xFFFFu);
            const bf16x8 hv0 = *(const bf16x8*)(hb + (long)d0 * FDIM + 8 * c);
            const float w0 = __half2float(__ushort_as_half((u16)(p0 >> 16)));
#pragma unroll
            for (int j = 0; j < 8; ++j) acc0[j] += w0 * (float)hv0[j];
            wsum0 += w0;
        }

        float acc[8];
#pragma unroll
        for (int j = 0; j < 8; ++j) acc[j] = (acc0[j] + acc1[j]) + (acc2[j] + acc3[j]);
        float wsum = (wsum0 + wsum1) + (wsum2 + wsum3);

#pragma unroll
        for (int off = 8; off < 64; off <<= 1) {
#pragma unroll
            for (int j = 0; j < 8; ++j) acc[j] += __shfl_xor(acc[j], off);
            wsum += __shfl_xor(wsum, off);
        }

        if (q == 0) {
            const float inv = 1.0f / wsum;
            float o[8];
#pragma unroll
            for (int j = 0; j < 8; ++j) {
                const float v = acc[j] * inv;
                o[j] = v > 0.f ? v : expm1f(v);
            }
            float* op = &out[(long)node * FDIM + 8 * c];
            *(float4*)op = make_float4(o[0], o[1], o[2], o[3]);
            *(float4*)(op + 4) = make_float4(o[4], o[5], o[6], o[7]);
        }
    }
}

extern "C" void kernel_launch(void* const* d_in, const int* in_sizes, int n_in,
                              void* d_out, int out_size, void* d_ws, size_t ws_size,
                              hipStream_t stream) {
    const float* x = (const float*)d_in[0];
    const float* W = (const float*)d_in[1];
    const float* a = (const float*)d_in[2];
    const int* ei  = (const int*)d_in[3];

    const int N = in_sizes[0] / KDIM;       // 50000
    const int E = in_sizes[3] / 2;          // 1600000
    const int NBU = (N + 63) >> 6;          // 782 buckets of 64 srcs
    const int NBLK = (E + BIN_CHUNK - 1) / BIN_CHUNK;  // 391 bin chunks
    const int GB = (N + 127) / 128;                    // 391 gemm blocks (128 rows)
    const int* srcA = ei;
    const int* dstA = ei + E;

    // workspace layout (all regions 16B aligned; ~20 MB)
    __hip_bfloat16* h_bf = (__hip_bfloat16*)d_ws;          // N*64 bf16
    __hip_bfloat16* w_t  = h_bf + (size_t)N * FDIM;        // 64*256 bf16
    float* s_src = (float*)(w_t + KDIM * FDIM);            // N
    float* s_dst = s_src + N;                              // N
    int* bcur    = (int*)(s_dst + N);                      // 1024 (zeroed by wt)
    u32* pair    = (u32*)(bcur + 1024);                    // NBU*CAP arena
    float* out   = (float*)d_out;

    gat_wt_kernel<<<dim3((KDIM * FDIM + 255) / 256), dim3(256), 0, stream>>>(
        W, w_t, bcur);

    gat_gemm_bin_kernel<<<dim3(NBLK + GB), dim3(512), 0, stream>>>(
        x, w_t, a, h_bf, s_src, s_dst, srcA, dstA, bcur, pair, N, E, NBU, NBLK);

    gat_sortgather_kernel<<<dim3(NBU), dim3(512), 0, stream>>>(
        pair, bcur, s_src, s_dst, h_bf, out, N);
}

// Round 5
// 180.445 us; speedup vs baseline: 1.0854x; 1.0854x over previous
//
#include <hip/hip_runtime.h>
#include <hip/hip_bf16.h>
#include <hip/hip_fp16.h>

// GAT layer on MI355X (gfx950).
//   x: (N=50000, K=256) fp32, W: (K=256, F=64) fp32, a: (1, 128) fp32
//   edge_index: (2, E=1600000) int (src row 0, dst row 1)
// out = elu( segsum_src(e * h[dst]) / segsum_src(e) ),
//   e = exp(-leakyrelu(s_src[src]+s_dst[dst], 0.2)), h = x@W
//
// Round 15: round-14's 4-stream gather regressed (deg~32 segments can't
// feed 4 streams -> drain-loop overhead; 52->67us). Reverted to round-12
// 2-stream. New parallelism WITHOUT extra atomics/write traffic:
//  K1: bin identical to round-12 (391 blocks, 4096-edge chunks, 64-buckets);
//      gemm split to 782 blocks x 64 rows (1 tile/wave, 256thr). 1173 blocks.
//  K2: two 256-thr blocks per bucket, each sorts+gathers 32 of the 64 nodes.
//      chunk[] staging dropped (two passes over L2-resident pair list) ->
//      LDS 33.8->9.7KB, 8 blocks/CU co-residency, 1564 blocks.

#define ALPHA 0.2f
#define KDIM 256
#define FDIM 64
#define BIN_CHUNK 4096
#define BUCKET_CAP 4096    // 64-src bucket: mean ~2046 edges; >40 sigma slack
#define HCAP 2304          // 32-src half bucket: mean ~1023; ~40 sigma slack

typedef __bf16 bf16x8 __attribute__((ext_vector_type(8)));
typedef float f32x4 __attribute__((ext_vector_type(4)));
typedef unsigned int u32;
typedef unsigned short u16;

// ---------------------------------------------------------------------------
// Kernel 0: w_t[n][k] = bf16(W[k][n]) (32 KB, L1-resident) + zero bcur.
// ---------------------------------------------------------------------------
__global__ __launch_bounds__(256) void gat_wt_kernel(
    const float* __restrict__ W, __hip_bfloat16* __restrict__ w_t,
    int* __restrict__ bcur)
{
    const int t = blockIdx.x * 256 + threadIdx.x;
    if (t < KDIM * FDIM) {
        const int k = t >> 6;
        const int n = t & 63;
        w_t[n * KDIM + k] = __float2bfloat16(W[t]);
    }
    if (t < 1024) bcur[t] = 0;
}

// ---------------------------------------------------------------------------
// Kernel 1 (fused): blocks [0,NBLK) = bin; blocks [NBLK, NBLK+GB) = gemm.
// 256 threads/block.
// bin: identical to verified round-12 config (local hist, one reservation
//      atomic per (block,bucket), packed scatter).
// gemm: 1 row-tile (16 rows) per wave, 4 waves -> 64 rows/block, 782 blocks.
// ---------------------------------------------------------------------------
__global__ __launch_bounds__(256) void gat_gemm_bin_kernel(
    const float* __restrict__ x, const __hip_bfloat16* __restrict__ w_tp,
    const float* __restrict__ a, __hip_bfloat16* __restrict__ h_bf,
    float* __restrict__ s_src, float* __restrict__ s_dst,
    const int* __restrict__ srcA, const int* __restrict__ dstA,
    int* __restrict__ bcur, u32* __restrict__ pair,
    int N, int E, int NBU, int NBLK)
{
    __shared__ int hist[1024];
    __shared__ int lcur[1024];

    const int t = threadIdx.x;

    if ((int)blockIdx.x < NBLK) {
        // ---------------- bin path ----------------
        for (int j = t; j < 1024; j += 256) hist[j] = 0;
        __syncthreads();
        const int base = blockIdx.x * BIN_CHUNK;
        const int cnt = min(BIN_CHUNK, E - base);
        for (int i = t; i < cnt; i += 256)
            atomicAdd(&hist[srcA[base + i] >> 6], 1);
        __syncthreads();
        for (int j = t; j < NBU; j += 256) {
            const int v = hist[j];
            lcur[j] = v ? (j * BUCKET_CAP + atomicAdd(&bcur[j], v)) : 0;
        }
        __syncthreads();
        for (int i = t; i < cnt; i += 256) {
            const int s = srcA[base + i];
            const int d = dstA[base + i];
            const int pos = atomicAdd(&lcur[s >> 6], 1);
            pair[pos] = ((u32)(s & 63) << 16) | (u32)d;   // d < 65536
        }
        return;
    }

    // ---------------- gemm path ----------------
    const int gb = (int)blockIdx.x - NBLK;
    const int lane = t & 63;
    const int wv = t >> 6;              // 0..3
    const int m0 = gb * 64 + wv * 16;   // this wave: rows m0..m0+15
    const int c = lane & 15;
    const int q = lane >> 4;

    const int r0 = m0 + c;
    const float* xp0 = x + (long)(r0 < N ? r0 : N - 1) * KDIM;
    const __bf16* wt = (const __bf16*)w_tp;

    f32x4 acc[4];
#pragma unroll
    for (int ct = 0; ct < 4; ++ct) acc[ct] = (f32x4){0.f, 0.f, 0.f, 0.f};

#pragma unroll 2
    for (int kc = 0; kc < 8; ++kc) {
        const int k0 = kc * 32 + q * 8;
        const float4 xa0 = *(const float4*)(xp0 + k0);
        const float4 xb0 = *(const float4*)(xp0 + k0 + 4);
        bf16x8 af0;
        af0[0] = (__bf16)xa0.x; af0[1] = (__bf16)xa0.y;
        af0[2] = (__bf16)xa0.z; af0[3] = (__bf16)xa0.w;
        af0[4] = (__bf16)xb0.x; af0[5] = (__bf16)xb0.y;
        af0[6] = (__bf16)xb0.z; af0[7] = (__bf16)xb0.w;
#pragma unroll
        for (int ct = 0; ct < 4; ++ct) {
            const bf16x8 bf = *(const bf16x8*)(wt + (ct * 16 + c) * KDIM + k0);
            acc[ct] = __builtin_amdgcn_mfma_f32_16x16x32_bf16(af0, bf, acc[ct], 0, 0, 0);
        }
    }

    float a1c[4], a2c[4];
#pragma unroll
    for (int ct = 0; ct < 4; ++ct) {
        a1c[ct] = a[ct * 16 + c];
        a2c[ct] = a[FDIM + ct * 16 + c];
    }

    float s1r[4], s2r[4];
#pragma unroll
    for (int reg = 0; reg < 4; ++reg) {
        float s1 = 0.f, s2 = 0.f;
#pragma unroll
        for (int ct = 0; ct < 4; ++ct) {
            s1 += acc[ct][reg] * a1c[ct];
            s2 += acc[ct][reg] * a2c[ct];
        }
        s1r[reg] = s1; s2r[reg] = s2;
    }
#pragma unroll
    for (int off = 1; off < 16; off <<= 1) {
#pragma unroll
        for (int reg = 0; reg < 4; ++reg) {
            s1r[reg] += __shfl_xor(s1r[reg], off);
            s2r[reg] += __shfl_xor(s2r[reg], off);
        }
    }
#pragma unroll
    for (int reg = 0; reg < 4; ++reg) {
        const int row = m0 + q * 4 + reg;
        if (row < N) {
#pragma unroll
            for (int ct = 0; ct < 4; ++ct)
                h_bf[(long)row * FDIM + ct * 16 + c] = __float2bfloat16(acc[ct][reg]);
            if (c == 0) { s_src[row] = s1r[reg]; s_dst[row] = s2r[reg]; }
        }
    }
}

// ---------------------------------------------------------------------------
// Kernel 2 (fused sort+gather, half-bucket blocks): 2 blocks (256 thr) per
// 64-src bucket; block handles 32 srcs (half = blockIdx&1).
// Phase A: two passes over the bucket's (L2-resident) pair list -- count
// matching srcs, scan, scatter directly into slds with packed f16 weight.
// Phase B: segmented reduction over bf16 h from the LDS edge list
// (2 independent edge streams per lane, round-12-verified loop).
// ---------------------------------------------------------------------------
__global__ __launch_bounds__(256) void gat_sortgather_kernel(
    const u32* __restrict__ pair, const int* __restrict__ bcur,
    const float* __restrict__ s_src, const float* __restrict__ s_dst,
    const __hip_bfloat16* __restrict__ h_bf, float* __restrict__ out, int N)
{
    __shared__ u32 slds[HCAP];   // 9 KB sorted (dst | f16(wgt)<<16)
    __shared__ int cur[32];
    __shared__ int nst[32];
    __shared__ int nen[32];
    __shared__ float ssl[32];

    const int b = (int)blockIdx.x >> 1;    // bucket
    const int hf = (int)blockIdx.x & 1;    // half: srcs [hf*32, hf*32+32)
    const int t = threadIdx.x;
    const int s0 = (b << 6) + (hf << 5);   // first src of this half
    const int abase = b * BUCKET_CAP;
    const int n = min(bcur[b], BUCKET_CAP);
    const int slo = hf << 5;               // src-lo range base within bucket

    if (t < 32) {
        cur[t] = 0;
        ssl[t] = (s0 + t < N) ? s_src[s0 + t] : 0.f;
    }
    __syncthreads();
    // pass 1: count srcs belonging to this half
    for (int i = t; i < n; i += 256) {
        const int sl = (int)(pair[abase + i] >> 16);
        if ((sl >> 5) == hf) atomicAdd(&cur[sl & 31], 1);
    }
    __syncthreads();
    if (t < 32) {   // lanes 0..31 of wave 0: exclusive scan of 32 counts
        const int v = cur[t];
        int incl = v;
#pragma unroll
        for (int off = 1; off < 32; off <<= 1) {
            const int nv = __shfl_up(incl, off);
            if (t >= off) incl += nv;
        }
        const int excl = incl - v;
        nst[t] = excl;
        nen[t] = min(excl + v, HCAP);
        cur[t] = excl;
    }
    __syncthreads();
    // pass 2: scatter matching edges into slds with packed weight
    for (int i = t; i < n; i += 256) {
        const u32 p = pair[abase + i];
        const int sl = (int)(p >> 16);
        if ((sl >> 5) != hf) continue;
        const int d = (int)(p & 0xFFFFu);
        const int slot = atomicAdd(&cur[sl & 31], 1);
        if (slot < HCAP) {
            const float sc = ssl[sl & 31] + s_dst[d];
            const float lr = sc > 0.f ? sc : ALPHA * sc;
            const float wgt = __expf(-lr);
            const u32 wh = (u32)__half_as_ushort(__float2half(wgt));
            slds[slot] = (u32)d | (wh << 16);
        }
    }
    __syncthreads();

    // ---------------- phase B: gather from LDS edge list ----------------
    const int wv = t >> 6;       // 0..3
    const int lane = t & 63;
    const int q = lane >> 3;     // edge slot 0..7
    const int c = lane & 7;      // feature octet 0..7
    const __bf16* hb = (const __bf16*)h_bf;

    for (int nl = wv; nl < 32; nl += 4) {
        const int node = s0 + nl;
        if (node >= N) break;
        const int start = nst[nl];
        const int end = nen[nl];

        float acc0[8], acc1[8];
#pragma unroll
        for (int j = 0; j < 8; ++j) { acc0[j] = 0.f; acc1[j] = 0.f; }
        float wsum0 = 0.f, wsum1 = 0.f;

        int e = start + q;
        for (; e + 8 < end; e += 16) {
            const u32 p0 = slds[e];
            const u32 p1 = slds[e + 8];
            const int d0 = (int)(p0 & 0xFFFFu);
            const int d1 = (int)(p1 & 0xFFFFu);
            const bf16x8 hv0 = *(const bf16x8*)(hb + (long)d0 * FDIM + 8 * c);
            const bf16x8 hv1 = *(const bf16x8*)(hb + (long)d1 * FDIM + 8 * c);
            const float w0 = __half2float(__ushort_as_half((u16)(p0 >> 16)));
            const float w1 = __half2float(__ushort_as_half((u16)(p1 >> 16)));
#pragma unroll
            for (int j = 0; j < 8; ++j) {
                acc0[j] += w0 * (float)hv0[j];
                acc1[j] += w1 * (float)hv1[j];
            }
            wsum0 += w0;
            wsum1 += w1;
        }
        if (e < end) {
            const u32 p0 = slds[e];
            const int d0 = (int)(p0 & 0xFFFFu);
            const bf16x8 hv0 = *(const bf16x8*)(hb + (long)d0 * FDIM + 8 * c);
            const float w0 = __half2float(__ushort_as_half((u16)(p0 >> 16)));
#pragma unroll
            for (int j = 0; j < 8; ++j) acc0[j] += w0 * (float)hv0[j];
            wsum0 += w0;
        }

        float acc[8];
#pragma unroll
        for (int j = 0; j < 8; ++j) acc[j] = acc0[j] + acc1[j];
        float wsum = wsum0 + wsum1;

#pragma unroll
        for (int off = 8; off < 64; off <<= 1) {
#pragma unroll
            for (int j = 0; j < 8; ++j) acc[j] += __shfl_xor(acc[j], off);
            wsum += __shfl_xor(wsum, off);
        }

        if (q == 0) {
            const float inv = 1.0f / wsum;
            float o[8];
#pragma unroll
            for (int j = 0; j < 8; ++j) {
                const float v = acc[j] * inv;
                o[j] = v > 0.f ? v : expm1f(v);
            }
            float* op = &out[(long)node * FDIM + 8 * c];
            *(float4*)op = make_float4(o[0], o[1], o[2], o[3]);
            *(float4*)(op + 4) = make_float4(o[4], o[5], o[6], o[7]);
        }
    }
}

extern "C" void kernel_launch(void* const* d_in, const int* in_sizes, int n_in,
                              void* d_out, int out_size, void* d_ws, size_t ws_size,
                              hipStream_t stream) {
    const float* x = (const float*)d_in[0];
    const float* W = (const float*)d_in[1];
    const float* a = (const float*)d_in[2];
    const int* ei  = (const int*)d_in[3];

    const int N = in_sizes[0] / KDIM;       // 50000
    const int E = in_sizes[3] / 2;          // 1600000
    const int NBU = (N + 63) >> 6;          // 782 buckets of 64 srcs
    const int NBLK = (E + BIN_CHUNK - 1) / BIN_CHUNK;  // 391 bin chunks
    const int GB = (N + 63) / 64;                      // 782 gemm blocks (64 rows)
    const int* srcA = ei;
    const int* dstA = ei + E;

    // workspace layout (all regions 16B aligned; ~20 MB)
    __hip_bfloat16* h_bf = (__hip_bfloat16*)d_ws;          // N*64 bf16
    __hip_bfloat16* w_t  = h_bf + (size_t)N * FDIM;        // 64*256 bf16
    float* s_src = (float*)(w_t + KDIM * FDIM);            // N
    float* s_dst = s_src + N;                              // N
    int* bcur    = (int*)(s_dst + N);                      // 1024 (zeroed by wt)
    u32* pair    = (u32*)(bcur + 1024);                    // NBU*CAP arena
    float* out   = (float*)d_out;

    gat_wt_kernel<<<dim3((KDIM * FDIM + 255) / 256), dim3(256), 0, stream>>>(
        W, w_t, bcur);

    gat_gemm_bin_kernel<<<dim3(NBLK + GB), dim3(256), 0, stream>>>(
        x, w_t, a, h_bf, s_src, s_dst, srcA, dstA, bcur, pair, N, E, NBU, NBLK);

    gat_sortgather_kernel<<<dim3(NBU * 2), dim3(256), 0, stream>>>(
        pair, bcur, s_src, s_dst, h_bf, out, N);
}

// Round 6
// 178.955 us; speedup vs baseline: 1.0945x; 1.0083x over previous
//
#include <hip/hip_runtime.h>
#include <hip/hip_bf16.h>
#include <hip/hip_fp16.h>

// GAT layer on MI355X (gfx950).
//   x: (N=50000, K=256) fp32, W: (K=256, F=64) fp32, a: (1, 128) fp32
//   edge_index: (2, E=1600000) int (src row 0, dst row 1)
// out = elu( segsum_src(e * h[dst]) / segsum_src(e) ),
//   e = exp(-leakyrelu(s_src[src]+s_dst[dst], 0.2)), h = x@W
//
// Round 16: K1 duration was invariant (~53us) across gemm reconfigs ->
// bin path is K1's critical path: 297K same-address reservation atomics
// (~380/bucket serialized) + 3x pair-scatter write amplification (5.2-edge
// runs). BIN_CHUNK 4096->8192: halves reservation atomics, doubles run
// length (42B ~ 1 line) -> pair writes ~20->12MB. Bin blocks 391->196,
// co-scheduled with 782 gemm blocks. K2 (half-bucket, verified round-15)
// and gemm path unchanged.

#define ALPHA 0.2f
#define KDIM 256
#define FDIM 64
#define BIN_CHUNK 8192
#define BUCKET_CAP 4096    // 64-src bucket: mean ~2046 edges; >40 sigma slack
#define HCAP 2304          // 32-src half bucket: mean ~1023; ~40 sigma slack

typedef __bf16 bf16x8 __attribute__((ext_vector_type(8)));
typedef float f32x4 __attribute__((ext_vector_type(4)));
typedef unsigned int u32;
typedef unsigned short u16;

// ---------------------------------------------------------------------------
// Kernel 0: w_t[n][k] = bf16(W[k][n]) (32 KB, L1-resident) + zero bcur.
// ---------------------------------------------------------------------------
__global__ __launch_bounds__(256) void gat_wt_kernel(
    const float* __restrict__ W, __hip_bfloat16* __restrict__ w_t,
    int* __restrict__ bcur)
{
    const int t = blockIdx.x * 256 + threadIdx.x;
    if (t < KDIM * FDIM) {
        const int k = t >> 6;
        const int n = t & 63;
        w_t[n * KDIM + k] = __float2bfloat16(W[t]);
    }
    if (t < 1024) bcur[t] = 0;
}

// ---------------------------------------------------------------------------
// Kernel 1 (fused): blocks [0,NBLK) = bin; blocks [NBLK, NBLK+GB) = gemm.
// 256 threads/block.
// bin: local hist over 8192-edge chunk, one reservation atomic per
//      (block,bucket) on bcur, packed scatter (srclo<<16)|dst.
// gemm: 1 row-tile (16 rows) per wave, 4 waves -> 64 rows/block, 782 blocks.
// ---------------------------------------------------------------------------
__global__ __launch_bounds__(256) void gat_gemm_bin_kernel(
    const float* __restrict__ x, const __hip_bfloat16* __restrict__ w_tp,
    const float* __restrict__ a, __hip_bfloat16* __restrict__ h_bf,
    float* __restrict__ s_src, float* __restrict__ s_dst,
    const int* __restrict__ srcA, const int* __restrict__ dstA,
    int* __restrict__ bcur, u32* __restrict__ pair,
    int N, int E, int NBU, int NBLK)
{
    __shared__ int hist[1024];
    __shared__ int lcur[1024];

    const int t = threadIdx.x;

    if ((int)blockIdx.x < NBLK) {
        // ---------------- bin path ----------------
        for (int j = t; j < 1024; j += 256) hist[j] = 0;
        __syncthreads();
        const int base = blockIdx.x * BIN_CHUNK;
        const int cnt = min(BIN_CHUNK, E - base);
        for (int i = t; i < cnt; i += 256)
            atomicAdd(&hist[srcA[base + i] >> 6], 1);
        __syncthreads();
        for (int j = t; j < NBU; j += 256) {
            const int v = hist[j];
            lcur[j] = v ? (j * BUCKET_CAP + atomicAdd(&bcur[j], v)) : 0;
        }
        __syncthreads();
        for (int i = t; i < cnt; i += 256) {
            const int s = srcA[base + i];
            const int d = dstA[base + i];
            const int pos = atomicAdd(&lcur[s >> 6], 1);
            pair[pos] = ((u32)(s & 63) << 16) | (u32)d;   // d < 65536
        }
        return;
    }

    // ---------------- gemm path ----------------
    const int gb = (int)blockIdx.x - NBLK;
    const int lane = t & 63;
    const int wv = t >> 6;              // 0..3
    const int m0 = gb * 64 + wv * 16;   // this wave: rows m0..m0+15
    const int c = lane & 15;
    const int q = lane >> 4;

    const int r0 = m0 + c;
    const float* xp0 = x + (long)(r0 < N ? r0 : N - 1) * KDIM;
    const __bf16* wt = (const __bf16*)w_tp;

    f32x4 acc[4];
#pragma unroll
    for (int ct = 0; ct < 4; ++ct) acc[ct] = (f32x4){0.f, 0.f, 0.f, 0.f};

#pragma unroll 2
    for (int kc = 0; kc < 8; ++kc) {
        const int k0 = kc * 32 + q * 8;
        const float4 xa0 = *(const float4*)(xp0 + k0);
        const float4 xb0 = *(const float4*)(xp0 + k0 + 4);
        bf16x8 af0;
        af0[0] = (__bf16)xa0.x; af0[1] = (__bf16)xa0.y;
        af0[2] = (__bf16)xa0.z; af0[3] = (__bf16)xa0.w;
        af0[4] = (__bf16)xb0.x; af0[5] = (__bf16)xb0.y;
        af0[6] = (__bf16)xb0.z; af0[7] = (__bf16)xb0.w;
#pragma unroll
        for (int ct = 0; ct < 4; ++ct) {
            const bf16x8 bf = *(const bf16x8*)(wt + (ct * 16 + c) * KDIM + k0);
            acc[ct] = __builtin_amdgcn_mfma_f32_16x16x32_bf16(af0, bf, acc[ct], 0, 0, 0);
        }
    }

    float a1c[4], a2c[4];
#pragma unroll
    for (int ct = 0; ct < 4; ++ct) {
        a1c[ct] = a[ct * 16 + c];
        a2c[ct] = a[FDIM + ct * 16 + c];
    }

    float s1r[4], s2r[4];
#pragma unroll
    for (int reg = 0; reg < 4; ++reg) {
        float s1 = 0.f, s2 = 0.f;
#pragma unroll
        for (int ct = 0; ct < 4; ++ct) {
            s1 += acc[ct][reg] * a1c[ct];
            s2 += acc[ct][reg] * a2c[ct];
        }
        s1r[reg] = s1; s2r[reg] = s2;
    }
#pragma unroll
    for (int off = 1; off < 16; off <<= 1) {
#pragma unroll
        for (int reg = 0; reg < 4; ++reg) {
            s1r[reg] += __shfl_xor(s1r[reg], off);
            s2r[reg] += __shfl_xor(s2r[reg], off);
        }
    }
#pragma unroll
    for (int reg = 0; reg < 4; ++reg) {
        const int row = m0 + q * 4 + reg;
        if (row < N) {
#pragma unroll
            for (int ct = 0; ct < 4; ++ct)
                h_bf[(long)row * FDIM + ct * 16 + c] = __float2bfloat16(acc[ct][reg]);
            if (c == 0) { s_src[row] = s1r[reg]; s_dst[row] = s2r[reg]; }
        }
    }
}

// ---------------------------------------------------------------------------
// Kernel 2 (fused sort+gather, half-bucket blocks): 2 blocks (256 thr) per
// 64-src bucket; block handles 32 srcs (half = blockIdx&1).
// Phase A: two passes over the bucket's (L2-resident) pair list -- count
// matching srcs, scan, scatter directly into slds with packed f16 weight.
// Phase B: segmented reduction over bf16 h from the LDS edge list
// (2 independent edge streams per lane).
// ---------------------------------------------------------------------------
__global__ __launch_bounds__(256) void gat_sortgather_kernel(
    const u32* __restrict__ pair, const int* __restrict__ bcur,
    const float* __restrict__ s_src, const float* __restrict__ s_dst,
    const __hip_bfloat16* __restrict__ h_bf, float* __restrict__ out, int N)
{
    __shared__ u32 slds[HCAP];   // 9 KB sorted (dst | f16(wgt)<<16)
    __shared__ int cur[32];
    __shared__ int nst[32];
    __shared__ int nen[32];
    __shared__ float ssl[32];

    const int b = (int)blockIdx.x >> 1;    // bucket
    const int hf = (int)blockIdx.x & 1;    // half: srcs [hf*32, hf*32+32)
    const int t = threadIdx.x;
    const int s0 = (b << 6) + (hf << 5);   // first src of this half
    const int abase = b * BUCKET_CAP;
    const int n = min(bcur[b], BUCKET_CAP);

    if (t < 32) {
        cur[t] = 0;
        ssl[t] = (s0 + t < N) ? s_src[s0 + t] : 0.f;
    }
    __syncthreads();
    // pass 1: count srcs belonging to this half
    for (int i = t; i < n; i += 256) {
        const int sl = (int)(pair[abase + i] >> 16);
        if ((sl >> 5) == hf) atomicAdd(&cur[sl & 31], 1);
    }
    __syncthreads();
    if (t < 32) {   // lanes 0..31 of wave 0: exclusive scan of 32 counts
        const int v = cur[t];
        int incl = v;
#pragma unroll
        for (int off = 1; off < 32; off <<= 1) {
            const int nv = __shfl_up(incl, off);
            if (t >= off) incl += nv;
        }
        const int excl = incl - v;
        nst[t] = excl;
        nen[t] = min(excl + v, HCAP);
        cur[t] = excl;
    }
    __syncthreads();
    // pass 2: scatter matching edges into slds with packed weight
    for (int i = t; i < n; i += 256) {
        const u32 p = pair[abase + i];
        const int sl = (int)(p >> 16);
        if ((sl >> 5) != hf) continue;
        const int d = (int)(p & 0xFFFFu);
        const int slot = atomicAdd(&cur[sl & 31], 1);
        if (slot < HCAP) {
            const float sc = ssl[sl & 31] + s_dst[d];
            const float lr = sc > 0.f ? sc : ALPHA * sc;
            const float wgt = __expf(-lr);
            const u32 wh = (u32)__half_as_ushort(__float2half(wgt));
            slds[slot] = (u32)d | (wh << 16);
        }
    }
    __syncthreads();

    // ---------------- phase B: gather from LDS edge list ----------------
    const int wv = t >> 6;       // 0..3
    const int lane = t & 63;
    const int q = lane >> 3;     // edge slot 0..7
    const int c = lane & 7;      // feature octet 0..7
    const __bf16* hb = (const __bf16*)h_bf;

    for (int nl = wv; nl < 32; nl += 4) {
        const int node = s0 + nl;
        if (node >= N) break;
        const int start = nst[nl];
        const int end = nen[nl];

        float acc0[8], acc1[8];
#pragma unroll
        for (int j = 0; j < 8; ++j) { acc0[j] = 0.f; acc1[j] = 0.f; }
        float wsum0 = 0.f, wsum1 = 0.f;

        int e = start + q;
        for (; e + 8 < end; e += 16) {
            const u32 p0 = slds[e];
            const u32 p1 = slds[e + 8];
            const int d0 = (int)(p0 & 0xFFFFu);
            const int d1 = (int)(p1 & 0xFFFFu);
            const bf16x8 hv0 = *(const bf16x8*)(hb + (long)d0 * FDIM + 8 * c);
            const bf16x8 hv1 = *(const bf16x8*)(hb + (long)d1 * FDIM + 8 * c);
            const float w0 = __half2float(__ushort_as_half((u16)(p0 >> 16)));
            const float w1 = __half2float(__ushort_as_half((u16)(p1 >> 16)));
#pragma unroll
            for (int j = 0; j < 8; ++j) {
                acc0[j] += w0 * (float)hv0[j];
                acc1[j] += w1 * (float)hv1[j];
            }
            wsum0 += w0;
            wsum1 += w1;
        }
        if (e < end) {
            const u32 p0 = slds[e];
            const int d0 = (int)(p0 & 0xFFFFu);
            const bf16x8 hv0 = *(const bf16x8*)(hb + (long)d0 * FDIM + 8 * c);
            const float w0 = __half2float(__ushort_as_half((u16)(p0 >> 16)));
#pragma unroll
            for (int j = 0; j < 8; ++j) acc0[j] += w0 * (float)hv0[j];
            wsum0 += w0;
        }

        float acc[8];
#pragma unroll
        for (int j = 0; j < 8; ++j) acc[j] = acc0[j] + acc1[j];
        float wsum = wsum0 + wsum1;

#pragma unroll
        for (int off = 8; off < 64; off <<= 1) {
#pragma unroll
            for (int j = 0; j < 8; ++j) acc[j] += __shfl_xor(acc[j], off);
            wsum += __shfl_xor(wsum, off);
        }

        if (q == 0) {
            const float inv = 1.0f / wsum;
            float o[8];
#pragma unroll
            for (int j = 0; j < 8; ++j) {
                const float v = acc[j] * inv;
                o[j] = v > 0.f ? v : expm1f(v);
            }
            float* op = &out[(long)node * FDIM + 8 * c];
            *(float4*)op = make_float4(o[0], o[1], o[2], o[3]);
            *(float4*)(op + 4) = make_float4(o[4], o[5], o[6], o[7]);
        }
    }
}

extern "C" void kernel_launch(void* const* d_in, const int* in_sizes, int n_in,
                              void* d_out, int out_size, void* d_ws, size_t ws_size,
                              hipStream_t stream) {
    const float* x = (const float*)d_in[0];
    const float* W = (const float*)d_in[1];
    const float* a = (const float*)d_in[2];
    const int* ei  = (const int*)d_in[3];

    const int N = in_sizes[0] / KDIM;       // 50000
    const int E = in_sizes[3] / 2;          // 1600000
    const int NBU = (N + 63) >> 6;          // 782 buckets of 64 srcs
    const int NBLK = (E + BIN_CHUNK - 1) / BIN_CHUNK;  // 196 bin chunks
    const int GB = (N + 63) / 64;                      // 782 gemm blocks (64 rows)
    const int* srcA = ei;
    const int* dstA = ei + E;

    // workspace layout (all regions 16B aligned; ~20 MB)
    __hip_bfloat16* h_bf = (__hip_bfloat16*)d_ws;          // N*64 bf16
    __hip_bfloat16* w_t  = h_bf + (size_t)N * FDIM;        // 64*256 bf16
    float* s_src = (float*)(w_t + KDIM * FDIM);            // N
    float* s_dst = s_src + N;                              // N
    int* bcur    = (int*)(s_dst + N);                      // 1024 (zeroed by wt)
    u32* pair    = (u32*)(bcur + 1024);                    // NBU*CAP arena
    float* out   = (float*)d_out;

    gat_wt_kernel<<<dim3((KDIM * FDIM + 255) / 256), dim3(256), 0, stream>>>(
        W, w_t, bcur);

    gat_gemm_bin_kernel<<<dim3(NBLK + GB), dim3(256), 0, stream>>>(
        x, w_t, a, h_bf, s_src, s_dst, srcA, dstA, bcur, pair, N, E, NBU, NBLK);

    gat_sortgather_kernel<<<dim3(NBU * 2), dim3(256), 0, stream>>>(
        pair, bcur, s_src, s_dst, h_bf, out, N);
}

// Round 8
// 169.648 us; speedup vs baseline: 1.1545x; 1.0549x over previous
//
#include <hip/hip_runtime.h>
#include <hip/hip_bf16.h>
#include <hip/hip_fp16.h>

// GAT layer on MI355X (gfx950).
//   x: (N=50000, K=256) fp32, W: (K=256, F=64) fp32, a: (1, 128) fp32
//   edge_index: (2, E=1600000) int (src row 0, dst row 1)
// out = elu( segsum_src(e * h[dst]) / segsum_src(e) ),
//   e = exp(-leakyrelu(s_src[src]+s_dst[dst], 0.2)), h = x@W
//
// Round 18: round-17 bench died on container infra (failed twice, no
// counters) -- resubmitting the same design unchanged to get the
// measurement. Structure: memset(bcur) + K_A (bin 196 blk | gemm 782 blk,
// W^T built per gemm block in 33KB LDS union) + K_B (half-bucket
// sort+gather, 1564 blk). 2 kernel dispatches total.

#define ALPHA 0.2f
#define KDIM 256
#define FDIM 64
#define WPAD 8             // bf16 row pad: row stride 264 elems = 528B
#define BIN_CHUNK 8192
#define BUCKET_CAP 4096    // 64-src bucket: mean ~2046 edges; >40 sigma slack
#define HCAP 2304          // 32-src half bucket: mean ~1023; ~40 sigma slack

typedef __bf16 bf16x8 __attribute__((ext_vector_type(8)));
typedef float f32x4 __attribute__((ext_vector_type(4)));
typedef unsigned int u32;
typedef unsigned short u16;

union SmemA {
    struct { int hist[1024]; int lcur[1024]; } bin;   // 8 KB
    __bf16 w[FDIM * (KDIM + WPAD)];                   // 33 KB  w[n][k]
};

// ---------------------------------------------------------------------------
// Kernel A (fused): blocks [0,NBLK) = bin; blocks [NBLK, NBLK+GB) = gemm.
// 256 threads/block.
// bin: local hist over 8192-edge chunk, one reservation atomic per
//      (block,bucket) on bcur, packed scatter (srclo<<16)|dst.
// gemm: per-block W^T in LDS (bf16, padded rows), then 1 row-tile (16 rows)
//       per wave via mfma_f32_16x16x32_bf16; 4 waves -> 64 rows/block.
// ---------------------------------------------------------------------------
__global__ __launch_bounds__(256) void gat_gemm_bin_kernel(
    const float* __restrict__ x, const float* __restrict__ W,
    const float* __restrict__ a, __hip_bfloat16* __restrict__ h_bf,
    float* __restrict__ s_src, float* __restrict__ s_dst,
    const int* __restrict__ srcA, const int* __restrict__ dstA,
    int* __restrict__ bcur, u32* __restrict__ pair,
    int N, int E, int NBU, int NBLK)
{
    __shared__ SmemA sm;
    const int t = threadIdx.x;

    if ((int)blockIdx.x < NBLK) {
        // ---------------- bin path ----------------
        for (int j = t; j < 1024; j += 256) sm.bin.hist[j] = 0;
        __syncthreads();
        const int base = blockIdx.x * BIN_CHUNK;
        const int cnt = min(BIN_CHUNK, E - base);
        for (int i = t; i < cnt; i += 256)
            atomicAdd(&sm.bin.hist[srcA[base + i] >> 6], 1);
        __syncthreads();
        for (int j = t; j < NBU; j += 256) {
            const int v = sm.bin.hist[j];
            sm.bin.lcur[j] = v ? (j * BUCKET_CAP + atomicAdd(&bcur[j], v)) : 0;
        }
        __syncthreads();
        for (int i = t; i < cnt; i += 256) {
            const int s = srcA[base + i];
            const int d = dstA[base + i];
            const int pos = atomicAdd(&sm.bin.lcur[s >> 6], 1);
            pair[pos] = ((u32)(s & 63) << 16) | (u32)d;   // d < 65536
        }
        return;
    }

    // ---------------- gemm path ----------------
    // Build w[n][k] = bf16(W[k][n]) in LDS (coalesced global read).
    for (int i = t; i < KDIM * FDIM; i += 256) {
        const int k = i >> 6;
        const int n = i & 63;
        sm.w[n * (KDIM + WPAD) + k] = (__bf16)W[i];
    }
    __syncthreads();

    const int gb = (int)blockIdx.x - NBLK;
    const int lane = t & 63;
    const int wv = t >> 6;              // 0..3
    const int m0 = gb * 64 + wv * 16;   // this wave: rows m0..m0+15
    const int c = lane & 15;
    const int q = lane >> 4;

    const int r0 = m0 + c;
    const float* xp0 = x + (long)(r0 < N ? r0 : N - 1) * KDIM;

    f32x4 acc[4];
#pragma unroll
    for (int ct = 0; ct < 4; ++ct) acc[ct] = (f32x4){0.f, 0.f, 0.f, 0.f};

#pragma unroll 4
    for (int kc = 0; kc < 8; ++kc) {
        const int k0 = kc * 32 + q * 8;
        const float4 xa0 = *(const float4*)(xp0 + k0);
        const float4 xb0 = *(const float4*)(xp0 + k0 + 4);
        bf16x8 af0;
        af0[0] = (__bf16)xa0.x; af0[1] = (__bf16)xa0.y;
        af0[2] = (__bf16)xa0.z; af0[3] = (__bf16)xa0.w;
        af0[4] = (__bf16)xb0.x; af0[5] = (__bf16)xb0.y;
        af0[6] = (__bf16)xb0.z; af0[7] = (__bf16)xb0.w;
#pragma unroll
        for (int ct = 0; ct < 4; ++ct) {
            const bf16x8 bf = *(const bf16x8*)(&sm.w[(ct * 16 + c) * (KDIM + WPAD) + k0]);
            acc[ct] = __builtin_amdgcn_mfma_f32_16x16x32_bf16(af0, bf, acc[ct], 0, 0, 0);
        }
    }

    float a1c[4], a2c[4];
#pragma unroll
    for (int ct = 0; ct < 4; ++ct) {
        a1c[ct] = a[ct * 16 + c];
        a2c[ct] = a[FDIM + ct * 16 + c];
    }

    float s1r[4], s2r[4];
#pragma unroll
    for (int reg = 0; reg < 4; ++reg) {
        float s1 = 0.f, s2 = 0.f;
#pragma unroll
        for (int ct = 0; ct < 4; ++ct) {
            s1 += acc[ct][reg] * a1c[ct];
            s2 += acc[ct][reg] * a2c[ct];
        }
        s1r[reg] = s1; s2r[reg] = s2;
    }
#pragma unroll
    for (int off = 1; off < 16; off <<= 1) {
#pragma unroll
        for (int reg = 0; reg < 4; ++reg) {
            s1r[reg] += __shfl_xor(s1r[reg], off);
            s2r[reg] += __shfl_xor(s2r[reg], off);
        }
    }
#pragma unroll
    for (int reg = 0; reg < 4; ++reg) {
        const int row = m0 + q * 4 + reg;
        if (row < N) {
#pragma unroll
            for (int ct = 0; ct < 4; ++ct)
                h_bf[(long)row * FDIM + ct * 16 + c] = __float2bfloat16(acc[ct][reg]);
            if (c == 0) { s_src[row] = s1r[reg]; s_dst[row] = s2r[reg]; }
        }
    }
}

// ---------------------------------------------------------------------------
// Kernel B (fused sort+gather, half-bucket blocks): 2 blocks (256 thr) per
// 64-src bucket; block handles 32 srcs (half = blockIdx&1).
// Phase A: two passes over the bucket's (L2-resident) pair list -- count
// matching srcs, scan, scatter directly into slds with packed f16 weight.
// Phase B: segmented reduction over bf16 h from the LDS edge list
// (2 independent edge streams per lane).
// ---------------------------------------------------------------------------
__global__ __launch_bounds__(256) void gat_sortgather_kernel(
    const u32* __restrict__ pair, const int* __restrict__ bcur,
    const float* __restrict__ s_src, const float* __restrict__ s_dst,
    const __hip_bfloat16* __restrict__ h_bf, float* __restrict__ out, int N)
{
    __shared__ u32 slds[HCAP];   // 9 KB sorted (dst | f16(wgt)<<16)
    __shared__ int cur[32];
    __shared__ int nst[32];
    __shared__ int nen[32];
    __shared__ float ssl[32];

    const int b = (int)blockIdx.x >> 1;    // bucket
    const int hf = (int)blockIdx.x & 1;    // half: srcs [hf*32, hf*32+32)
    const int t = threadIdx.x;
    const int s0 = (b << 6) + (hf << 5);   // first src of this half
    const int abase = b * BUCKET_CAP;
    const int n = min(bcur[b], BUCKET_CAP);

    if (t < 32) {
        cur[t] = 0;
        ssl[t] = (s0 + t < N) ? s_src[s0 + t] : 0.f;
    }
    __syncthreads();
    // pass 1: count srcs belonging to this half
    for (int i = t; i < n; i += 256) {
        const int sl = (int)(pair[abase + i] >> 16);
        if ((sl >> 5) == hf) atomicAdd(&cur[sl & 31], 1);
    }
    __syncthreads();
    if (t < 32) {   // lanes 0..31 of wave 0: exclusive scan of 32 counts
        const int v = cur[t];
        int incl = v;
#pragma unroll
        for (int off = 1; off < 32; off <<= 1) {
            const int nv = __shfl_up(incl, off);
            if (t >= off) incl += nv;
        }
        const int excl = incl - v;
        nst[t] = excl;
        nen[t] = min(excl + v, HCAP);
        cur[t] = excl;
    }
    __syncthreads();
    // pass 2: scatter matching edges into slds with packed weight
    for (int i = t; i < n; i += 256) {
        const u32 p = pair[abase + i];
        const int sl = (int)(p >> 16);
        if ((sl >> 5) != hf) continue;
        const int d = (int)(p & 0xFFFFu);
        const int slot = atomicAdd(&cur[sl & 31], 1);
        if (slot < HCAP) {
            const float sc = ssl[sl & 31] + s_dst[d];
            const float lr = sc > 0.f ? sc : ALPHA * sc;
            const float wgt = __expf(-lr);
            const u32 wh = (u32)__half_as_ushort(__float2half(wgt));
            slds[slot] = (u32)d | (wh << 16);
        }
    }
    __syncthreads();

    // ---------------- phase B: gather from LDS edge list ----------------
    const int wv = t >> 6;       // 0..3
    const int lane = t & 63;
    const int q = lane >> 3;     // edge slot 0..7
    const int c = lane & 7;      // feature octet 0..7
    const __bf16* hb = (const __bf16*)h_bf;

    for (int nl = wv; nl < 32; nl += 4) {
        const int node = s0 + nl;
        if (node >= N) break;
        const int start = nst[nl];
        const int end = nen[nl];

        float acc0[8], acc1[8];
#pragma unroll
        for (int j = 0; j < 8; ++j) { acc0[j] = 0.f; acc1[j] = 0.f; }
        float wsum0 = 0.f, wsum1 = 0.f;

        int e = start + q;
        for (; e + 8 < end; e += 16) {
            const u32 p0 = slds[e];
            const u32 p1 = slds[e + 8];
            const int d0 = (int)(p0 & 0xFFFFu);
            const int d1 = (int)(p1 & 0xFFFFu);
            const bf16x8 hv0 = *(const bf16x8*)(hb + (long)d0 * FDIM + 8 * c);
            const bf16x8 hv1 = *(const bf16x8*)(hb + (long)d1 * FDIM + 8 * c);
            const float w0 = __half2float(__ushort_as_half((u16)(p0 >> 16)));
            const float w1 = __half2float(__ushort_as_half((u16)(p1 >> 16)));
#pragma unroll
            for (int j = 0; j < 8; ++j) {
                acc0[j] += w0 * (float)hv0[j];
                acc1[j] += w1 * (float)hv1[j];
            }
            wsum0 += w0;
            wsum1 += w1;
        }
        if (e < end) {
            const u32 p0 = slds[e];
            const int d0 = (int)(p0 & 0xFFFFu);
            const bf16x8 hv0 = *(const bf16x8*)(hb + (long)d0 * FDIM + 8 * c);
            const float w0 = __half2float(__ushort_as_half((u16)(p0 >> 16)));
#pragma unroll
            for (int j = 0; j < 8; ++j) acc0[j] += w0 * (float)hv0[j];
            wsum0 += w0;
        }

        float acc[8];
#pragma unroll
        for (int j = 0; j < 8; ++j) acc[j] = acc0[j] + acc1[j];
        float wsum = wsum0 + wsum1;

#pragma unroll
        for (int off = 8; off < 64; off <<= 1) {
#pragma unroll
            for (int j = 0; j < 8; ++j) acc[j] += __shfl_xor(acc[j], off);
            wsum += __shfl_xor(wsum, off);
        }

        if (q == 0) {
            const float inv = 1.0f / wsum;
            float o[8];
#pragma unroll
            for (int j = 0; j < 8; ++j) {
                const float v = acc[j] * inv;
                o[j] = v > 0.f ? v : expm1f(v);
            }
            float* op = &out[(long)node * FDIM + 8 * c];
            *(float4*)op = make_float4(o[0], o[1], o[2], o[3]);
            *(float4*)(op + 4) = make_float4(o[4], o[5], o[6], o[7]);
        }
    }
}

extern "C" void kernel_launch(void* const* d_in, const int* in_sizes, int n_in,
                              void* d_out, int out_size, void* d_ws, size_t ws_size,
                              hipStream_t stream) {
    const float* x = (const float*)d_in[0];
    const float* W = (const float*)d_in[1];
    const float* a = (const float*)d_in[2];
    const int* ei  = (const int*)d_in[3];

    const int N = in_sizes[0] / KDIM;       // 50000
    const int E = in_sizes[3] / 2;          // 1600000
    const int NBU = (N + 63) >> 6;          // 782 buckets of 64 srcs
    const int NBLK = (E + BIN_CHUNK - 1) / BIN_CHUNK;  // 196 bin chunks
    const int GB = (N + 63) / 64;                      // 782 gemm blocks (64 rows)
    const int* srcA = ei;
    const int* dstA = ei + E;

    // workspace layout (all regions 16B aligned; ~16 MB)
    __hip_bfloat16* h_bf = (__hip_bfloat16*)d_ws;          // N*64 bf16
    float* s_src = (float*)(h_bf + (size_t)N * FDIM);      // N
    float* s_dst = s_src + N;                              // N
    int* bcur    = (int*)(s_dst + N);                      // 1024
    u32* pair    = (u32*)(bcur + 1024);                    // NBU*CAP arena
    float* out   = (float*)d_out;

    hipMemsetAsync(bcur, 0, 1024 * sizeof(int), stream);

    gat_gemm_bin_kernel<<<dim3(NBLK + GB), dim3(256), 0, stream>>>(
        x, W, a, h_bf, s_src, s_dst, srcA, dstA, bcur, pair, N, E, NBU, NBLK);

    gat_sortgather_kernel<<<dim3(NBU * 2), dim3(256), 0, stream>>>(
        pair, bcur, s_src, s_dst, h_bf, out, N);
}